// Round 1
// baseline (1078.858 us; speedup 1.0000x reference)
//
#include <hip/hip_runtime.h>

// Problem constants (from reference)
#define NN     50000
#define NFEAT  512
#define HIDD   128
#define NE     1600000

// ---------------------------------------------------------------------------
// CSR build: histogram -> exclusive scan -> scatter
// ---------------------------------------------------------------------------
__global__ __launch_bounds__(256) void hist_kernel(
    const int* __restrict__ row, int* __restrict__ counts, int e) {
  int i = blockIdx.x * blockDim.x + threadIdx.x;
  if (i < e) atomicAdd(&counts[row[i]], 1);
}

// Single-block exclusive scan over n ints. counts_inout becomes exclusive
// prefix (reused as write-ptr), rowptr gets exclusive prefix + rowptr[n]=total.
__global__ __launch_bounds__(1024) void scan_kernel(
    int* __restrict__ counts_inout, int* __restrict__ rowptr, int n) {
  __shared__ int wsum[16];
  __shared__ int s_running;
  int tid = threadIdx.x;
  int lane = tid & 63, wid = tid >> 6;
  if (tid == 0) s_running = 0;
  __syncthreads();
  for (int base = 0; base < n; base += 1024) {
    int i = base + tid;
    int v = (i < n) ? counts_inout[i] : 0;
    int incl = v;
#pragma unroll
    for (int off = 1; off < 64; off <<= 1) {
      int t = __shfl_up(incl, off, 64);
      if (lane >= off) incl += t;
    }
    if (lane == 63) wsum[wid] = incl;
    __syncthreads();
    if (tid < 16) {
      int s = wsum[tid];
#pragma unroll
      for (int off = 1; off < 16; off <<= 1) {
        int t = __shfl_up(s, off, 16);
        if (tid >= off) s += t;
      }
      wsum[tid] = s;
    }
    __syncthreads();
    int waveoff = (wid == 0) ? 0 : wsum[wid - 1];
    int run = s_running;
    int excl = run + waveoff + (incl - v);
    if (i < n) { rowptr[i] = excl; counts_inout[i] = excl; }
    __syncthreads();  // all reads of s_running/wsum done
    if (tid == 0) s_running = run + wsum[15];
    __syncthreads();
  }
  if (tid == 0) rowptr[n] = s_running;
}

__global__ __launch_bounds__(256) void scatter_kernel(
    const int* __restrict__ row, const int* __restrict__ col,
    const float* __restrict__ val, int* __restrict__ wptr,
    int* __restrict__ cols_s, float* __restrict__ vals_s, int e) {
  int i = blockIdx.x * blockDim.x + threadIdx.x;
  if (i < e) {
    int p = atomicAdd(&wptr[row[i]], 1);
    cols_s[p] = col[i];
    vals_s[p] = val[i];
  }
}

// ---------------------------------------------------------------------------
// CSR SpMM, D=128. One 32-lane group per row, float4 per lane.
// Optional fused bias+relu epilogue.
// ---------------------------------------------------------------------------
template <bool EPI>
__global__ __launch_bounds__(256) void spmm_kernel(
    const int* __restrict__ rowptr, const int* __restrict__ cols,
    const float* __restrict__ vals, const float* __restrict__ dense,
    const float* __restrict__ bias, float* __restrict__ out, int n) {
  int r = blockIdx.x * 8 + (threadIdx.x >> 5);
  if (r >= n) return;
  int c4 = (threadIdx.x & 31);  // float4 index within row
  const float4* dense4 = (const float4*)dense;
  int s = rowptr[r], e = rowptr[r + 1];
  float4 acc = make_float4(0.f, 0.f, 0.f, 0.f);
  for (int j = s; j < e; ++j) {
    int ci = cols[j];
    float v = vals[j];
    float4 d = dense4[(size_t)ci * 32 + c4];
    acc.x = fmaf(v, d.x, acc.x);
    acc.y = fmaf(v, d.y, acc.y);
    acc.z = fmaf(v, d.z, acc.z);
    acc.w = fmaf(v, d.w, acc.w);
  }
  if (EPI) {
    float4 b = *(const float4*)(bias + c4 * 4);
    acc.x = fmaxf(acc.x + b.x, 0.f);
    acc.y = fmaxf(acc.y + b.y, 0.f);
    acc.z = fmaxf(acc.z + b.z, 0.f);
    acc.w = fmaxf(acc.w + b.w, 0.f);
  }
  *(float4*)(out + (size_t)r * 128 + c4 * 4) = acc;
}

// ---------------------------------------------------------------------------
// fp32 tiled GEMM: C[M,Ncols] = A[M,K] @ B[K,Ncols]  (+bias, relu if EPI)
// BM=64, BN=128, BK=32, 256 threads, 8x4 micro-tile per thread.
// ---------------------------------------------------------------------------
template <int K, bool EPI>
__global__ __launch_bounds__(256) void gemm_kernel(
    const float* __restrict__ A, const float* __restrict__ B,
    const float* __restrict__ bias, float* __restrict__ C,
    int M, int Ncols) {
  constexpr int BM = 64, BN = 128, BK = 32;
  __shared__ __align__(16) float As[BK][BM + 4];  // transposed A tile
  __shared__ __align__(16) float Bs[BK][BN];
  int tid = threadIdx.x;
  int tx = tid & 31;   // col group (4 cols)
  int ty = tid >> 5;   // row group (8 rows)
  int rowBase = blockIdx.x * BM;
  int colBase = blockIdx.y * BN;
  float acc[8][4] = {};
  for (int kb = 0; kb < K; kb += BK) {
    // A tile: 64x32 floats = 512 float4
#pragma unroll
    for (int s = 0; s < 2; ++s) {
      int q = tid + s * 256;
      int r = q >> 3;
      int kq = (q & 7) * 4;
      float4 v = make_float4(0.f, 0.f, 0.f, 0.f);
      int gr = rowBase + r;
      if (gr < M) v = *(const float4*)(A + (size_t)gr * K + kb + kq);
      As[kq + 0][r] = v.x;
      As[kq + 1][r] = v.y;
      As[kq + 2][r] = v.z;
      As[kq + 3][r] = v.w;
    }
    // B tile: 32x128 floats = 1024 float4
#pragma unroll
    for (int s = 0; s < 4; ++s) {
      int q = tid + s * 256;
      int kr = q >> 5;
      int cq = (q & 31) * 4;
      float4 v = *(const float4*)(B + (size_t)(kb + kr) * Ncols + colBase + cq);
      *(float4*)&Bs[kr][cq] = v;
    }
    __syncthreads();
#pragma unroll
    for (int kk = 0; kk < BK; ++kk) {
      float4 a0 = *(const float4*)&As[kk][ty * 8];
      float4 a1 = *(const float4*)&As[kk][ty * 8 + 4];
      float4 b0 = *(const float4*)&Bs[kk][tx * 4];
      float av[8] = {a0.x, a0.y, a0.z, a0.w, a1.x, a1.y, a1.z, a1.w};
      float bv[4] = {b0.x, b0.y, b0.z, b0.w};
#pragma unroll
      for (int i = 0; i < 8; ++i)
#pragma unroll
        for (int j = 0; j < 4; ++j)
          acc[i][j] = fmaf(av[i], bv[j], acc[i][j]);
    }
    __syncthreads();
  }
#pragma unroll
  for (int i = 0; i < 8; ++i) {
    int gr = rowBase + ty * 8 + i;
    if (gr < M) {
      int gc = colBase + tx * 4;
      float4 o;
      o.x = acc[i][0]; o.y = acc[i][1]; o.z = acc[i][2]; o.w = acc[i][3];
      if (EPI) {
        o.x = fmaxf(o.x + bias[gc + 0], 0.f);
        o.y = fmaxf(o.y + bias[gc + 1], 0.f);
        o.z = fmaxf(o.z + bias[gc + 2], 0.f);
        o.w = fmaxf(o.w + bias[gc + 3], 0.f);
      }
      *(float4*)(C + (size_t)gr * Ncols + gc) = o;
    }
  }
}

// ---------------------------------------------------------------------------
extern "C" void kernel_launch(void* const* d_in, const int* in_sizes, int n_in,
                              void* d_out, int out_size, void* d_ws, size_t ws_size,
                              hipStream_t stream) {
  const float* x        = (const float*)d_in[0];
  const int*   adj_row  = (const int*)d_in[1];
  const int*   adj_col  = (const int*)d_in[2];
  const float* adj_val  = (const float*)d_in[3];
  const int*   ainv_row = (const int*)d_in[4];
  const int*   ainv_col = (const int*)d_in[5];
  const float* ainv_val = (const float*)d_in[6];
  const float* W1       = (const float*)d_in[7];
  const float* b1       = (const float*)d_in[8];
  const float* W2       = (const float*)d_in[9];
  const float* b2       = (const float*)d_in[10];

  float* out = (float*)d_out;                    // [N,512]
  float* emb = out + (size_t)NN * NFEAT;         // [N,128]

  // Workspace carve (~52 MB)
  float* H0       = (float*)d_ws;                // [N,128], later reused as T
  int*   rowptr_a = (int*)(H0 + (size_t)NN * HIDD);
  int*   rowptr_b = rowptr_a + 50004;
  int*   wptr_a   = rowptr_b + 50004;
  int*   wptr_b   = wptr_a + 50004;
  int*   cols_a   = wptr_b + 50004;
  float* vals_a   = (float*)(cols_a + NE);
  int*   cols_b   = (int*)(vals_a + NE);
  float* vals_b   = (float*)(cols_b + NE);
  float* T        = H0;  // alias: H0 dead by the time T is written

  // ---- CSR build for both graphs ----
  hipMemsetAsync(wptr_a, 0, 50004 * sizeof(int), stream);
  hipMemsetAsync(wptr_b, 0, 50004 * sizeof(int), stream);
  hist_kernel<<<NE / 256, 256, 0, stream>>>(adj_row, wptr_a, NE);
  hist_kernel<<<NE / 256, 256, 0, stream>>>(ainv_row, wptr_b, NE);
  scan_kernel<<<1, 1024, 0, stream>>>(wptr_a, rowptr_a, NN);
  scan_kernel<<<1, 1024, 0, stream>>>(wptr_b, rowptr_b, NN);
  scatter_kernel<<<NE / 256, 256, 0, stream>>>(adj_row, adj_col, adj_val,
                                               wptr_a, cols_a, vals_a, NE);
  scatter_kernel<<<NE / 256, 256, 0, stream>>>(ainv_row, ainv_col, ainv_val,
                                               wptr_b, cols_b, vals_b, NE);

  // ---- H0 = X @ W1 ----
  gemm_kernel<NFEAT, false><<<dim3((NN + 63) / 64, 1), 256, 0, stream>>>(
      x, W1, nullptr, H0, NN, HIDD);

  // ---- emb = relu(A @ H0 + b1) ----
  spmm_kernel<true><<<(NN + 7) / 8, 256, 0, stream>>>(
      rowptr_a, cols_a, vals_a, H0, b1, emb, NN);

  // ---- T = A_inv @ emb  (reassociated: (A_inv @ h) @ W2) ----
  spmm_kernel<false><<<(NN + 7) / 8, 256, 0, stream>>>(
      rowptr_b, cols_b, vals_b, emb, nullptr, T, NN);

  // ---- out = relu(T @ W2 + b2) ----
  gemm_kernel<HIDD, true><<<dim3((NN + 63) / 64, 4), 256, 0, stream>>>(
      T, W2, b2, out, NN, NFEAT);
}